// Round 7
// baseline (32.256 us; speedup 1.0000x reference)
//
#include <hip/hip_runtime.h>

#define SLEN   300
#define PT     20
#define STEP   4
#define MAXD   2
#define NBANDS 2
#define NS     30
#define NGAL   8
#define BATCH  8
#define N1     71            // (300-20)/4+1
#define NPT    (N1*N1)       // 5041
#define NSUB   (BATCH*NPT)   // 40328

// ---- output layout (flat float32, in reference return order) ----
#define OFF_LOCS 32262400
#define OFF_GAL  32423712
#define OFF_FLUX 33068960
#define OFF_N    33230272
#define OFF_ISON 33270600

// tiling decomposition: one block per (batch, patch-row i, j-quarter)
#define JQ   4
#define NJQ  18                               // j's per quarter (last has 17)
#define TILE_BLOCKS (BATCH * N1 * JQ)         // 2272 = 8 * 284
#define CAT_BLOCKS  ((NSUB + 255) / 256)      // 158
#define CHUNK (TILE_BLOCKS / 8)               // 284 blocks per XCD

typedef float vf4 __attribute__((ext_vector_type(4)));
typedef float vf2 __attribute__((ext_vector_type(2)));

// Round-5 structure (28.2 us) with ONE change: nontemporal stores on the
// 129 MB patch stream (+ catalog outputs), so the write stream doesn't
// write-allocate in the 4 MiB per-XCD L2 and evict the image strip the
// gather loop re-reads 25x.
__global__ __launch_bounds__(256) void fused_kernel(
    const float* __restrict__ img,
    const float* __restrict__ locs,
    const float* __restrict__ gal,
    const float* __restrict__ flux,
    float* __restrict__ out)
{
    const int bid = blockIdx.x;
    const int tid = threadIdx.x;

    if (bid < TILE_BLOCKS) {
        // ---------------- patch extraction (direct L1/L2-cached reads) -----
        const int wg = (bid & 7) * CHUNK + (bid >> 3);   // bijective XCD swizzle
        const int jq = wg & 3;
        const int bi = wg >> 2;
        const int i  = bi % N1;
        const int b  = bi / N1;
        const int j0 = jq * NJQ;
        const int nj = (jq == 3) ? (N1 - 3 * NJQ) : NJQ;   // 17 or 18
        const int col0 = j0 * STEP;
        const int i4   = i * STEP;

        const int sub0 = b * NPT + i * N1 + j0;
        vf4* dst = reinterpret_cast<vf4*>(out) + (size_t)sub0 * 200;
        const float* imb = img + (size_t)b * NBANDS * SLEN * SLEN
                               + (size_t)i4 * SLEN + col0;
        const int tot = nj * 200;   // within-chunk w == jj*200 + c*100 + rr*5 + q

        for (int w = tid; w < tot; w += 256) {
            int jj  = w / 200;
            int rem = w - jj * 200;
            int c   = rem / 100;
            int r2  = rem - c * 100;
            int rr  = r2 / 5;
            int q   = r2 - rr * 5;
            const vf4 v = *reinterpret_cast<const vf4*>(
                imb + ((size_t)(c * SLEN + rr)) * SLEN + jj * 4 + q * 4);
            __builtin_nontemporal_store(v, dst + w);
        }
    } else {
        // ---------------- per-tile catalog ----------------
        const int sub = (bid - TILE_BLOCKS) * 256 + tid;
        if (sub >= NSUB) return;

        const int b = sub / NPT;
        const int t = sub % NPT;
        const int i = t / N1;
        const int j = t % N1;

        const float lox = (float)(i * STEP) + 1.5f;   // tc.x + EP - 0.5
        const float loy = (float)(j * STEP) + 1.5f;
        const float hix = lox + 16.0f;                // tc - 0.5 + PT - EP
        const float hiy = loy + 16.0f;

        int   cnt = 0;
        int   sid[2] = {0, 0};
        float slx[2] = {0.f, 0.f};
        float sly[2] = {0.f, 0.f};

        const float* lb = locs + (size_t)b * NS * 2;
        #pragma unroll
        for (int s = 0; s < NS; ++s) {
            float lx = lb[2 * s + 0] * (float)(SLEN - 1);
            float ly = lb[2 * s + 1] * (float)(SLEN - 1);
            bool on = (lx > lox) && (lx < hix) && (ly > loy) && (ly < hiy);
            if (on) {
                if (cnt < MAXD) { sid[cnt] = s; slx[cnt] = lx; sly[cnt] = ly; }
                cnt++;
            }
        }

        const float inv_scale = 1.0f / 16.0f;  // 1/(PT-2*EP), exact

        vf4 lv;
        lv.x = (cnt > 0) ? fmaxf((slx[0] - lox) * inv_scale, 0.0f) : 0.0f;
        lv.y = (cnt > 0) ? fmaxf((sly[0] - loy) * inv_scale, 0.0f) : 0.0f;
        lv.z = (cnt > 1) ? fmaxf((slx[1] - lox) * inv_scale, 0.0f) : 0.0f;
        lv.w = (cnt > 1) ? fmaxf((sly[1] - loy) * inv_scale, 0.0f) : 0.0f;
        __builtin_nontemporal_store(lv, reinterpret_cast<vf4*>(out + OFF_LOCS) + sub);

        vf4 g0 = {0,0,0,0}, g1 = {0,0,0,0}, g2 = {0,0,0,0}, g3 = {0,0,0,0};
        if (cnt > 0) {
            const vf4* gp = reinterpret_cast<const vf4*>(
                gal + ((size_t)(b * NS + sid[0])) * NGAL);
            g0 = gp[0]; g1 = gp[1];
        }
        if (cnt > 1) {
            const vf4* gp = reinterpret_cast<const vf4*>(
                gal + ((size_t)(b * NS + sid[1])) * NGAL);
            g2 = gp[0]; g3 = gp[1];
        }
        vf4* go = reinterpret_cast<vf4*>(out + OFF_GAL) + (size_t)sub * 4;
        __builtin_nontemporal_store(g0, go + 0);
        __builtin_nontemporal_store(g1, go + 1);
        __builtin_nontemporal_store(g2, go + 2);
        __builtin_nontemporal_store(g3, go + 3);

        vf4 fv = {0,0,0,0};
        if (cnt > 0) {
            const vf2 f = *reinterpret_cast<const vf2*>(
                flux + ((size_t)(b * NS + sid[0])) * NBANDS);
            fv.x = f.x; fv.y = f.y;
        }
        if (cnt > 1) {
            const vf2 f = *reinterpret_cast<const vf2*>(
                flux + ((size_t)(b * NS + sid[1])) * NBANDS);
            fv.z = f.x; fv.w = f.y;
        }
        __builtin_nontemporal_store(fv, reinterpret_cast<vf4*>(out + OFF_FLUX) + sub);

        __builtin_nontemporal_store((float)(cnt < MAXD ? cnt : MAXD), out + OFF_N + sub);
        vf2 ison;
        ison.x = (cnt > 0) ? 1.0f : 0.0f;
        ison.y = (cnt > 1) ? 1.0f : 0.0f;
        __builtin_nontemporal_store(ison, reinterpret_cast<vf2*>(out + OFF_ISON) + sub);
    }
}

extern "C" void kernel_launch(void* const* d_in, const int* in_sizes, int n_in,
                              void* d_out, int out_size, void* d_ws, size_t ws_size,
                              hipStream_t stream)
{
    const float* images = (const float*)d_in[0];
    const float* locs   = (const float*)d_in[1];
    const float* gal    = (const float*)d_in[2];
    const float* flux   = (const float*)d_in[3];
    float* out = (float*)d_out;

    fused_kernel<<<TILE_BLOCKS + CAT_BLOCKS, 256, 0, stream>>>(
        images, locs, gal, flux, out);
}

// Round 8
// 29.591 us; speedup vs baseline: 1.0901x; 1.0901x over previous
//
#include <hip/hip_runtime.h>

#define SLEN   300
#define PT     20
#define STEP   4
#define MAXD   2
#define NBANDS 2
#define NS     30
#define NGAL   8
#define BATCH  8
#define N1     71            // (300-20)/4+1
#define NPT    (N1*N1)       // 5041
#define NSUB   (BATCH*NPT)   // 40328

// ---- output layout (flat float32, in reference return order) ----
#define OFF_LOCS 32262400
#define OFF_GAL  32423712
#define OFF_FLUX 33068960
#define OFF_N    33230272
#define OFF_ISON 33270600

// tiling decomposition: one block per (batch, patch-row i, j-quarter)
#define JQ   4
#define NJQ  18                               // j's per quarter (last has 17)
#define TILE_BLOCKS (BATCH * N1 * JQ)         // 2272 = 8 * 284
#define CAT_BLOCKS  ((NSUB + 255) / 256)      // 158
#define CHUNK (TILE_BLOCKS / 8)               // 284 blocks per XCD

typedef float vf4 __attribute__((ext_vector_type(4)));

// Round-5 structure (28.2 us), ONE change: slot-restructured emit loop.
// Lane (<200) owns a fixed (c,rr,q) slot; loops over jj with constant
// address increments (load +16B, store +3200B) — no per-iteration division,
// and each lane re-walks the same image row (4x 16B-granule reuse across jj,
// L1-friendly). Plain stores (NT measured -4us in R7).
__global__ __launch_bounds__(256) void fused_kernel(
    const float* __restrict__ img,
    const float* __restrict__ locs,
    const float* __restrict__ gal,
    const float* __restrict__ flux,
    float* __restrict__ out)
{
    const int bid = blockIdx.x;
    const int tid = threadIdx.x;

    if (bid < TILE_BLOCKS) {
        // ---------------- patch extraction (direct L1/L2-cached reads) -----
        if (tid >= 200) return;              // 200 slots = (c,rr,q)
        const int wg = (bid & 7) * CHUNK + (bid >> 3);   // bijective XCD swizzle
        const int jq = wg & 3;
        const int bi = wg >> 2;
        const int i  = bi % N1;
        const int b  = bi / N1;
        const int j0 = jq * NJQ;
        const int nj = (jq == 3) ? (N1 - 3 * NJQ) : NJQ;   // 17 or 18

        const int c  = tid / 100;            // band
        const int r2 = tid - c * 100;
        const int rr = r2 / 5;               // patch row
        const int q  = r2 - rr * 5;          // float4 within row

        const int sub0 = b * NPT + i * N1 + j0;
        // store: within-chunk index = jj*200 + slot, walk 200 f4 per jj
        vf4* dst = reinterpret_cast<vf4*>(out) + (size_t)sub0 * 200 + tid;
        // load: img[b, c, i*4+rr, j0*4 + jj*4 + q*4 ..], walk 4 floats per jj
        const float* src = img
            + (size_t)((b * NBANDS + c) * SLEN + i * STEP + rr) * SLEN
            + j0 * STEP + q * 4;

        #pragma unroll 6
        for (int jj = 0; jj < nj; ++jj) {
            *dst = *reinterpret_cast<const vf4*>(src);
            dst += 200;
            src += 4;
        }
    } else {
        // ---------------- per-tile catalog ----------------
        const int sub = (bid - TILE_BLOCKS) * 256 + tid;
        if (sub >= NSUB) return;

        const int b = sub / NPT;
        const int t = sub % NPT;
        const int i = t / N1;
        const int j = t % N1;

        const float lox = (float)(i * STEP) + 1.5f;   // tc.x + EP - 0.5
        const float loy = (float)(j * STEP) + 1.5f;
        const float hix = lox + 16.0f;                // tc - 0.5 + PT - EP
        const float hiy = loy + 16.0f;

        int   cnt = 0;
        int   sid[2] = {0, 0};
        float slx[2] = {0.f, 0.f};
        float sly[2] = {0.f, 0.f};

        const float* lb = locs + (size_t)b * NS * 2;
        #pragma unroll
        for (int s = 0; s < NS; ++s) {
            float lx = lb[2 * s + 0] * (float)(SLEN - 1);
            float ly = lb[2 * s + 1] * (float)(SLEN - 1);
            bool on = (lx > lox) && (lx < hix) && (ly > loy) && (ly < hiy);
            if (on) {
                if (cnt < MAXD) { sid[cnt] = s; slx[cnt] = lx; sly[cnt] = ly; }
                cnt++;
            }
        }

        const float inv_scale = 1.0f / 16.0f;  // 1/(PT-2*EP), exact

        float4 lv;
        lv.x = (cnt > 0) ? fmaxf((slx[0] - lox) * inv_scale, 0.0f) : 0.0f;
        lv.y = (cnt > 0) ? fmaxf((sly[0] - loy) * inv_scale, 0.0f) : 0.0f;
        lv.z = (cnt > 1) ? fmaxf((slx[1] - lox) * inv_scale, 0.0f) : 0.0f;
        lv.w = (cnt > 1) ? fmaxf((sly[1] - loy) * inv_scale, 0.0f) : 0.0f;
        reinterpret_cast<float4*>(out + OFF_LOCS)[sub] = lv;

        float4 g0 = {0,0,0,0}, g1 = {0,0,0,0}, g2 = {0,0,0,0}, g3 = {0,0,0,0};
        if (cnt > 0) {
            const float4* gp = reinterpret_cast<const float4*>(
                gal + ((size_t)(b * NS + sid[0])) * NGAL);
            g0 = gp[0]; g1 = gp[1];
        }
        if (cnt > 1) {
            const float4* gp = reinterpret_cast<const float4*>(
                gal + ((size_t)(b * NS + sid[1])) * NGAL);
            g2 = gp[0]; g3 = gp[1];
        }
        float4* go = reinterpret_cast<float4*>(out + OFF_GAL) + (size_t)sub * 4;
        go[0] = g0; go[1] = g1; go[2] = g2; go[3] = g3;

        float4 fv = {0,0,0,0};
        if (cnt > 0) {
            const float2 f = reinterpret_cast<const float2*>(
                flux + ((size_t)(b * NS + sid[0])) * NBANDS)[0];
            fv.x = f.x; fv.y = f.y;
        }
        if (cnt > 1) {
            const float2 f = reinterpret_cast<const float2*>(
                flux + ((size_t)(b * NS + sid[1])) * NBANDS)[0];
            fv.z = f.x; fv.w = f.y;
        }
        reinterpret_cast<float4*>(out + OFF_FLUX)[sub] = fv;

        out[OFF_N + sub] = (float)(cnt < MAXD ? cnt : MAXD);
        float2 ison;
        ison.x = (cnt > 0) ? 1.0f : 0.0f;
        ison.y = (cnt > 1) ? 1.0f : 0.0f;
        reinterpret_cast<float2*>(out + OFF_ISON)[sub] = ison;
    }
}

extern "C" void kernel_launch(void* const* d_in, const int* in_sizes, int n_in,
                              void* d_out, int out_size, void* d_ws, size_t ws_size,
                              hipStream_t stream)
{
    const float* images = (const float*)d_in[0];
    const float* locs   = (const float*)d_in[1];
    const float* gal    = (const float*)d_in[2];
    const float* flux   = (const float*)d_in[3];
    float* out = (float*)d_out;

    fused_kernel<<<TILE_BLOCKS + CAT_BLOCKS, 256, 0, stream>>>(
        images, locs, gal, flux, out);
}

// Round 9
// 27.097 us; speedup vs baseline: 1.1904x; 1.0921x over previous
//
#include <hip/hip_runtime.h>

#define SLEN   300
#define PT     20
#define STEP   4
#define MAXD   2
#define NBANDS 2
#define NS     30
#define NGAL   8
#define BATCH  8
#define N1     71            // (300-20)/4+1
#define NPT    (N1*N1)       // 5041
#define NSUB   (BATCH*NPT)   // 40328

// ---- output layout (flat float32, in reference return order) ----
#define OFF_LOCS 32262400
#define OFF_GAL  32423712
#define OFF_FLUX 33068960
#define OFF_N    33230272
#define OFF_ISON 33270600

// Single-round grid: 1136 tile blocks (one per (b,i,half-row), each emitting
// 35 or 36 patches with R5's proven w-loop) + 158 catalog blocks = 1294
// blocks < 2048 resident capacity -> every block starts at t=0, no second
// dispatch round, catalog overlaps the store stream instead of trailing it.
#define TILE_BLOCKS (BATCH * N1 * 2)          // 1136 = 8 * 142
#define CAT_BLOCKS  ((NSUB + 255) / 256)      // 158
#define CHUNK (TILE_BLOCKS / 8)               // 142 blocks per XCD (= 1 batch)

typedef float vf4 __attribute__((ext_vector_type(4)));

__global__ __launch_bounds__(256) void fused_kernel(
    const float* __restrict__ img,
    const float* __restrict__ locs,
    const float* __restrict__ gal,
    const float* __restrict__ flux,
    float* __restrict__ out)
{
    const int bid = blockIdx.x;
    const int tid = threadIdx.x;

    if (bid < TILE_BLOCKS) {
        // ---------------- patch extraction (direct L1/L2-cached reads) -----
        // XCD swizzle: 1136 = 8*142; XCD k gets contiguous chunk == batch k
        // (image footprint 720 KB, L2-resident).
        const int wg = (bid & 7) * CHUNK + (bid >> 3);
        const int h  = wg & 1;               // half of the i-row (j 0..35 / 36..70)
        const int bi = wg >> 1;
        const int i  = bi % N1;
        const int b  = bi / N1;
        const int j0 = h * 36;
        const int nj = h ? 35 : 36;
        const int col0 = j0 * STEP;
        const int i4   = i * STEP;

        const int sub0 = b * NPT + i * N1 + j0;
        vf4* dst = reinterpret_cast<vf4*>(out) + (size_t)sub0 * 200;
        const float* imb = img + (size_t)b * NBANDS * SLEN * SLEN
                               + (size_t)i4 * SLEN + col0;
        const int tot = nj * 200;   // within-chunk w == jj*200 + c*100 + rr*5 + q

        for (int w = tid; w < tot; w += 256) {
            int jj  = w / 200;
            int rem = w - jj * 200;
            int c   = rem / 100;
            int r2  = rem - c * 100;
            int rr  = r2 / 5;
            int q   = r2 - rr * 5;
            const vf4 v = *reinterpret_cast<const vf4*>(
                imb + ((size_t)(c * SLEN + rr)) * SLEN + jj * 4 + q * 4);
            dst[w] = v;
        }
    } else {
        // ---------------- per-tile catalog ----------------
        const int sub = (bid - TILE_BLOCKS) * 256 + tid;
        if (sub >= NSUB) return;

        const int b = sub / NPT;
        const int t = sub % NPT;
        const int i = t / N1;
        const int j = t % N1;

        const float lox = (float)(i * STEP) + 1.5f;   // tc.x + EP - 0.5
        const float loy = (float)(j * STEP) + 1.5f;
        const float hix = lox + 16.0f;                // tc - 0.5 + PT - EP
        const float hiy = loy + 16.0f;

        int   cnt = 0;
        int   sid[2] = {0, 0};
        float slx[2] = {0.f, 0.f};
        float sly[2] = {0.f, 0.f};

        const float* lb = locs + (size_t)b * NS * 2;
        #pragma unroll
        for (int s = 0; s < NS; ++s) {
            float lx = lb[2 * s + 0] * (float)(SLEN - 1);
            float ly = lb[2 * s + 1] * (float)(SLEN - 1);
            bool on = (lx > lox) && (lx < hix) && (ly > loy) && (ly < hiy);
            if (on) {
                if (cnt < MAXD) { sid[cnt] = s; slx[cnt] = lx; sly[cnt] = ly; }
                cnt++;
            }
        }

        const float inv_scale = 1.0f / 16.0f;  // 1/(PT-2*EP), exact

        float4 lv;
        lv.x = (cnt > 0) ? fmaxf((slx[0] - lox) * inv_scale, 0.0f) : 0.0f;
        lv.y = (cnt > 0) ? fmaxf((sly[0] - loy) * inv_scale, 0.0f) : 0.0f;
        lv.z = (cnt > 1) ? fmaxf((slx[1] - lox) * inv_scale, 0.0f) : 0.0f;
        lv.w = (cnt > 1) ? fmaxf((sly[1] - loy) * inv_scale, 0.0f) : 0.0f;
        reinterpret_cast<float4*>(out + OFF_LOCS)[sub] = lv;

        float4 g0 = {0,0,0,0}, g1 = {0,0,0,0}, g2 = {0,0,0,0}, g3 = {0,0,0,0};
        if (cnt > 0) {
            const float4* gp = reinterpret_cast<const float4*>(
                gal + ((size_t)(b * NS + sid[0])) * NGAL);
            g0 = gp[0]; g1 = gp[1];
        }
        if (cnt > 1) {
            const float4* gp = reinterpret_cast<const float4*>(
                gal + ((size_t)(b * NS + sid[1])) * NGAL);
            g2 = gp[0]; g3 = gp[1];
        }
        float4* go = reinterpret_cast<float4*>(out + OFF_GAL) + (size_t)sub * 4;
        go[0] = g0; go[1] = g1; go[2] = g2; go[3] = g3;

        float4 fv = {0,0,0,0};
        if (cnt > 0) {
            const float2 f = reinterpret_cast<const float2*>(
                flux + ((size_t)(b * NS + sid[0])) * NBANDS)[0];
            fv.x = f.x; fv.y = f.y;
        }
        if (cnt > 1) {
            const float2 f = reinterpret_cast<const float2*>(
                flux + ((size_t)(b * NS + sid[1])) * NBANDS)[0];
            fv.z = f.x; fv.w = f.y;
        }
        reinterpret_cast<float4*>(out + OFF_FLUX)[sub] = fv;

        out[OFF_N + sub] = (float)(cnt < MAXD ? cnt : MAXD);
        float2 ison;
        ison.x = (cnt > 0) ? 1.0f : 0.0f;
        ison.y = (cnt > 1) ? 1.0f : 0.0f;
        reinterpret_cast<float2*>(out + OFF_ISON)[sub] = ison;
    }
}

extern "C" void kernel_launch(void* const* d_in, const int* in_sizes, int n_in,
                              void* d_out, int out_size, void* d_ws, size_t ws_size,
                              hipStream_t stream)
{
    const float* images = (const float*)d_in[0];
    const float* locs   = (const float*)d_in[1];
    const float* gal    = (const float*)d_in[2];
    const float* flux   = (const float*)d_in[3];
    float* out = (float*)d_out;

    fused_kernel<<<TILE_BLOCKS + CAT_BLOCKS, 256, 0, stream>>>(
        images, locs, gal, flux, out);
}